// Round 5
// baseline (144.415 us; speedup 1.0000x reference)
//
#include <hip/hip_runtime.h>
#include <hip/hip_bf16.h>

#define NH   8
#define HID  256
#define VD   32
#define NQ   2048
#define NKK  2048
#define NB   16
#define NN   512   // NB*VD

typedef short bf16x8 __attribute__((ext_vector_type(8)));
typedef float f32x4 __attribute__((ext_vector_type(4)));

__device__ inline unsigned short f2bf(float f) {
  unsigned int u = __float_as_uint(f);
  u += 0x7FFFu + ((u >> 16) & 1u);   // RNE
  return (unsigned short)(u >> 16);
}

__device__ inline void gload_lds16(const void* g, void* l) {
  __builtin_amdgcn_global_load_lds(
      (const __attribute__((address_space(1))) void*)g,
      (__attribute__((address_space(3))) void*)l, 16, 0, 0);
}

__device__ inline float gelu_f(float x) {
  // jax.nn.gelu approximate: 0.5x(1+tanh(u)), tanh via exp (2u in [-20,20], no overflow)
  float u2 = 1.5957691216057308f * (x + 0.044715f * x * x * x);  // 2u
  float e = __expf(u2);
  return 0.5f * x * (1.0f + (e - 1.0f) / (e + 1.0f));
}

// LDS tile swizzle (T2): 16B slot s of row r holds logical slot s ^ ((r>>1)&3).

// ---------------- fused dispatch: blocks 0..511 = value GEMM, 512..16895 = att rows
__global__ __launch_bounds__(256) void fused_va_kernel(
    const float* __restrict__ x, const float* __restrict__ w,
    const float* __restrict__ m_dist, const float* __restrict__ r,
    unsigned short* __restrict__ vT, unsigned short* __restrict__ att) {
  __shared__ __align__(16) char smem[16384];
  const int t = threadIdx.x;

  if (blockIdx.x < 512) {
    // ======== value branch: vT[(h,v)][k] = sum_j bf16(w[h][j][v]) * bf16(x[b][k][j])
    const int vb  = blockIdx.x;
    const int hvt = vb & 1;              // hv tile (0..1)
    const int kt  = (vb >> 1) & 15;      // k tile (0..15)
    const int b   = vb >> 5;             // batch (0..15)
    const int m0 = hvt * 128;
    const int n0 = kt * 128;
    const int lane = t & 63, wid = t >> 6;
    const int wr = wid >> 1, wc = wid & 1;

    unsigned short* As = (unsigned short*)smem;            // 8 KB
    unsigned short* Bs = (unsigned short*)(smem + 8192);   // 8 KB

    // A staging: load w f32 directly (L2-hot, 128 KB total), convert, swizzled ds_write
    const int arow = t >> 1;             // 0..127 (hv row)
    const int ahalf = t & 1;             // j half (16 elems)
    const int hh = (m0 + arow) >> 5, avv = (m0 + arow) & 31;
    const float* wbase = w + ((size_t)hh * HID + ahalf * 16) * VD + avv;
    const int ac = (arow >> 1) & 3;
    unsigned short* wA0 = (unsigned short*)((char*)As + arow * 64 + (((2 * ahalf) ^ ac) * 16));
    unsigned short* wA1 = (unsigned short*)((char*)As + arow * 64 + (((2 * ahalf + 1) ^ ac) * 16));

    // B staging via registers with f32->bf16 (x rows are k-cols of output)
    const int brow = t >> 1, bj = (t & 1) * 16;
    const float* gB = x + ((size_t)b * NKK + n0 + brow) * HID + bj;
    const int bc = (brow >> 1) & 3;
    const int bs0 = (2 * (t & 1)) ^ bc;
    unsigned short* lB0 = Bs + brow * 32 + bs0 * 8;
    unsigned short* lB1 = Bs + brow * 32 + ((bs0 ^ 1)) * 8;

    f32x4 acc[4][4];
#pragma unroll
    for (int i = 0; i < 4; ++i)
#pragma unroll
      for (int j = 0; j < 4; ++j) acc[i][j] = (f32x4){0.f, 0.f, 0.f, 0.f};

    const int fr = lane & 15;
    const int kb = (((lane >> 4) ^ ((fr >> 1) & 3)) * 16);
    const char* baseA = (const char*)As + (wr * 64 + fr) * 64 + kb;
    const char* baseB = (const char*)Bs + (wc * 64 + fr) * 64 + kb;

    // prefetch B step 0
    f32x4 p0 = *(const f32x4*)(gB + 0);
    f32x4 p1 = *(const f32x4*)(gB + 4);
    f32x4 p2 = *(const f32x4*)(gB + 8);
    f32x4 p3 = *(const f32x4*)(gB + 12);

    for (int kk = 0; kk < HID / 32; ++kk) {
      // A: 16 strided f32 loads (stride 128B) from w
      float av[16];
#pragma unroll
      for (int e = 0; e < 16; ++e) av[e] = wbase[((size_t)kk * 32 + e) * VD];

      f32x4 c0 = p0, c1 = p1, c2 = p2, c3 = p3;
      if (kk < HID / 32 - 1) {
        const float* nb = gB + (kk + 1) * 32;
        p0 = *(const f32x4*)(nb + 0);
        p1 = *(const f32x4*)(nb + 4);
        p2 = *(const f32x4*)(nb + 8);
        p3 = *(const f32x4*)(nb + 12);
      }
      uint4 qa0, qa1;
      qa0.x = (unsigned)f2bf(av[0]) | ((unsigned)f2bf(av[1]) << 16);
      qa0.y = (unsigned)f2bf(av[2]) | ((unsigned)f2bf(av[3]) << 16);
      qa0.z = (unsigned)f2bf(av[4]) | ((unsigned)f2bf(av[5]) << 16);
      qa0.w = (unsigned)f2bf(av[6]) | ((unsigned)f2bf(av[7]) << 16);
      qa1.x = (unsigned)f2bf(av[8]) | ((unsigned)f2bf(av[9]) << 16);
      qa1.y = (unsigned)f2bf(av[10]) | ((unsigned)f2bf(av[11]) << 16);
      qa1.z = (unsigned)f2bf(av[12]) | ((unsigned)f2bf(av[13]) << 16);
      qa1.w = (unsigned)f2bf(av[14]) | ((unsigned)f2bf(av[15]) << 16);
      *(uint4*)wA0 = qa0;
      *(uint4*)wA1 = qa1;

      uint4 pk0, pk1;
      pk0.x = (unsigned)f2bf(c0[0]) | ((unsigned)f2bf(c0[1]) << 16);
      pk0.y = (unsigned)f2bf(c0[2]) | ((unsigned)f2bf(c0[3]) << 16);
      pk0.z = (unsigned)f2bf(c1[0]) | ((unsigned)f2bf(c1[1]) << 16);
      pk0.w = (unsigned)f2bf(c1[2]) | ((unsigned)f2bf(c1[3]) << 16);
      pk1.x = (unsigned)f2bf(c2[0]) | ((unsigned)f2bf(c2[1]) << 16);
      pk1.y = (unsigned)f2bf(c2[2]) | ((unsigned)f2bf(c2[3]) << 16);
      pk1.z = (unsigned)f2bf(c3[0]) | ((unsigned)f2bf(c3[1]) << 16);
      pk1.w = (unsigned)f2bf(c3[2]) | ((unsigned)f2bf(c3[3]) << 16);
      *(uint4*)lB0 = pk0;
      *(uint4*)lB1 = pk1;

      __syncthreads();

      bf16x8 a[4], bfr[4];
#pragma unroll
      for (int i = 0; i < 4; ++i) a[i] = *(const bf16x8*)(baseA + i * 16 * 64);
#pragma unroll
      for (int j = 0; j < 4; ++j) bfr[j] = *(const bf16x8*)(baseB + j * 16 * 64);
#pragma unroll
      for (int i = 0; i < 4; ++i)
#pragma unroll
        for (int j = 0; j < 4; ++j)
          acc[i][j] = __builtin_amdgcn_mfma_f32_16x16x32_bf16(a[i], bfr[j], acc[i][j], 0, 0, 0);
      __syncthreads();
    }

    const int hvb = m0 + wr * 64 + (lane >> 4) * 4;
    const int kc0 = n0 + wc * 64 + (lane & 15);
#pragma unroll
    for (int i = 0; i < 4; ++i) {
#pragma unroll
      for (int j = 0; j < 4; ++j) {
        int kc = kc0 + j * 16;
#pragma unroll
        for (int e = 0; e < 4; ++e) {
          int hv = hvb + i * 16 + e;
          int h = hv >> 5, v = hv & 31;
          vT[((size_t)h * NN + b * VD + v) * NKK + kc] = f2bf(acc[i][j][e]);
        }
      }
    }
  } else {
    // ======== att branch: per (h,q) row: median threshold + masked softmax -> att bf16
    const int row = blockIdx.x - 512;    // h*NQ + q
    const int h = row >> 11;
    const int wid = t >> 6;
    const float* md = m_dist + (size_t)row * NKK;

    unsigned int* hist = (unsigned int*)smem;            // 1024 B
    float* coll = (float*)(smem + 1024);                 // 640 B
    unsigned int* su = (unsigned int*)(smem + 1664);     // [0]=collCnt [1]=sBA [2]=sBB [3]=sBelow [4..7]=wtot
    float* sf = (float*)(smem + 1696);                   // [0..3]=wmin [4..7]=wsumsh [8]=sVa [9]=sVb

    float rr = r[h];
    const float C = (float)(0.25 * 3.141592653589793 * (1.0 - 1e-7));
    float sc = tanf(C * (1.0f + sinf(rr)));

    hist[t] = 0u;
    if (t == 0) su[0] = 0u;
    __syncthreads();

    float m[8];
#pragma unroll
    for (int j = 0; j < 8; ++j) m[j] = md[t + 256 * j];

    float mn = m[0];
#pragma unroll
    for (int j = 1; j < 8; ++j) mn = fminf(mn, m[j]);
#pragma unroll
    for (int j = 0; j < 8; ++j) {
      int bin = (int)(m[j] * 256.0f);
      bin = min(max(bin, 0), 255);
      atomicAdd(&hist[bin], 1u);
    }
#pragma unroll
    for (int off = 32; off > 0; off >>= 1) mn = fminf(mn, __shfl_down(mn, off));
    if ((t & 63) == 0) sf[wid] = mn;
    __syncthreads();

    unsigned int c = hist[t];
    unsigned int xs2 = c;
    for (int off = 1; off < 64; off <<= 1) {
      unsigned int y = __shfl_up(xs2, off);
      if ((t & 63) >= off) xs2 += y;
    }
    if ((t & 63) == 63) su[4 + wid] = xs2;
    __syncthreads();
    unsigned int base = 0;
    for (int wq = 0; wq < 4; ++wq)
      if (wq < wid) base += su[4 + wq];
    unsigned int cum = xs2 + base;
    if (cum >= 1024u && cum - c < 1024u) { su[1] = (unsigned)t; su[3] = cum - c; }
    if (cum >= 1025u && cum - c < 1025u) { su[2] = (unsigned)t; }
    __syncthreads();

    const int bA = (int)su[1], bB = (int)su[2];
    const unsigned int below = su[3];
#pragma unroll
    for (int j = 0; j < 8; ++j) {
      int bin = (int)(m[j] * 256.0f);
      bin = min(max(bin, 0), 255);
      if (bin >= bA && bin <= bB) {
        unsigned int idx = atomicAdd(&su[0], 1u);
        if (idx < 160u) coll[idx] = m[j];
      }
    }
    __syncthreads();
    const int n = (int)min(su[0], 160u);
    const int ra = 1023 - (int)below, rb = 1024 - (int)below;
    if (t < n) {
      float v = coll[t];
      int rank = 0;
      for (int j2 = 0; j2 < n; ++j2) {
        float u = coll[j2];
        rank += (u < v || (u == v && j2 < t)) ? 1 : 0;  // stable rank
      }
      if (rank == ra) sf[8] = v;
      if (rank == rb) sf[9] = v;
    }
    __syncthreads();

    float mtot = fminf(fminf(sf[0], sf[1]), fminf(sf[2], sf[3]));
    float minscaled = mtot * sc;
    float thr = 0.5f * (sf[8] * sc) + 0.5f * (sf[9] * sc);

    float wv[8];
    float wsum = 0.f;
#pragma unroll
    for (int j = 0; j < 8; ++j) {
      float s = m[j] * sc;
      float e = (s <= thr) ? __expf(minscaled - s) : 0.f;
      wv[j] = e;
      wsum += e;
    }
#pragma unroll
    for (int off = 32; off > 0; off >>= 1) wsum += __shfl_down(wsum, off);
    if ((t & 63) == 0) sf[4 + wid] = wsum;
    __syncthreads();
    float denom = sf[4] + sf[5] + sf[6] + sf[7];
    float inv = 1.0f / denom;

    unsigned short* ao = att + (size_t)row * NKK;
#pragma unroll
    for (int j = 0; j < 8; ++j) ao[t + 256 * j] = f2bf(wv[j] * inv);
  }
}

// ---------------- kernel 2: per head GEMM: C[q, n] = att[h] @ vT[h]^T, + gelu, scattered out
// depth-3 pipelined: 4 LDS buffer pairs, counted vmcnt(8), one barrier per K-step
__global__ __launch_bounds__(256) void gemm_kernel(
    const unsigned short* __restrict__ att, const unsigned short* __restrict__ vT,
    float* __restrict__ out) {
  const int bid = blockIdx.x;
  const int h = bid & 7;           // XCD = bid%8 -> one head per XCD (B panel L2-resident)
  const int tile = bid >> 3;       // 0..63
  const int qt = tile >> 2, nt = tile & 3;
  const int q0 = qt * 128, n0 = nt * 128;
  const int t = threadIdx.x;
  const int lane = t & 63, wid = t >> 6;
  const int wr = wid >> 1, wc = wid & 1;

  __shared__ __align__(16) unsigned short As[4][128 * 32];
  __shared__ __align__(16) unsigned short Bs[4][128 * 32];

  const int rowL = t >> 2;          // 0..63
  const int cb = (((t & 3) ^ ((t >> 3) & 3)) * 8);   // pre-swizzled source k offset

  const unsigned short* gA = att + ((size_t)h * NQ + q0 + rowL) * NKK + cb;
  const unsigned short* gB = vT + ((size_t)h * NN + n0 + rowL) * NKK + cb;
  const int ldsOff = t * 16;

#define STAGE(BI, KT) do {                                                  \
    const unsigned short* a_ = gA + (KT) * 32;                              \
    const unsigned short* b_ = gB + (KT) * 32;                              \
    char* lA_ = (char*)As[(BI)] + ldsOff;                                   \
    char* lB_ = (char*)Bs[(BI)] + ldsOff;                                   \
    gload_lds16(a_, lA_);                                                   \
    gload_lds16(a_ + (size_t)64 * NKK, lA_ + 4096);                         \
    gload_lds16(b_, lB_);                                                   \
    gload_lds16(b_ + (size_t)64 * NKK, lB_ + 4096);                         \
  } while (0)

  f32x4 acc[4][4];
#pragma unroll
  for (int i = 0; i < 4; ++i)
#pragma unroll
    for (int j = 0; j < 4; ++j) acc[i][j] = (f32x4){0.f, 0.f, 0.f, 0.f};

  const int fr = lane & 15;
  const int kb = (((lane >> 4) ^ ((fr >> 1) & 3)) * 16);   // swizzled read slot
  const int fragOff = (wr * 64 + fr) * 64 + kb;   // A-side byte offset
  const int fragOffB = (wc * 64 + fr) * 64 + kb;  // B-side byte offset

  // prologue: 3 tiles in flight
  STAGE(0, 0);
  STAGE(1, 1);
  STAGE(2, 2);
  asm volatile("s_waitcnt vmcnt(8)\n\ts_barrier" ::: "memory");  // tile 0 ready

  for (int kt = 0; kt < 64; kt += 4) {
#pragma unroll
    for (int u = 0; u < 4; ++u) {
      // frag reads from buffer u (tile kt+u)
      const char* bA = (const char*)As[u] + fragOff;
      const char* bB = (const char*)Bs[u] + fragOffB;
      bf16x8 a[4], b[4];
#pragma unroll
      for (int i = 0; i < 4; ++i) a[i] = *(const bf16x8*)(bA + i * 1024);
#pragma unroll
      for (int j = 0; j < 4; ++j) b[j] = *(const bf16x8*)(bB + j * 1024);
      // stage tile kt+u+3 into buffer (u+3)&3 (consumed last sub-iter); wrap at tail
      STAGE((u + 3) & 3, (kt + u + 3) & 63);
      __builtin_amdgcn_s_setprio(1);
#pragma unroll
      for (int i = 0; i < 4; ++i)
#pragma unroll
        for (int j = 0; j < 4; ++j)
          acc[i][j] = __builtin_amdgcn_mfma_f32_16x16x32_bf16(a[i], b[j], acc[i][j], 0, 0, 0);
      __builtin_amdgcn_s_setprio(0);
      // keep 8 loads (2 tiles) in flight; oldest tile (next to read) retired
      asm volatile("s_waitcnt vmcnt(8)\n\ts_barrier" ::: "memory");
    }
  }
  // drain junk tail stages before LDS deallocates / epilogue
  asm volatile("s_waitcnt vmcnt(0)" ::: "memory");
#undef STAGE

  // epilogue: D row=(lane>>4)*4+reg, col=lane&15 ; n -> (b, v) ; out[b, q, h*32+v]
  const int orow = q0 + wr * 64 + (lane >> 4) * 4;
  const int ocol0 = n0 + wc * 64 + (lane & 15);
#pragma unroll
  for (int i = 0; i < 4; ++i) {
#pragma unroll
    for (int j = 0; j < 4; ++j) {
      int ncol = ocol0 + j * 16;
      int bb = ncol >> 5, vv = ncol & 31;
      float* op = out + ((size_t)bb * NQ + orow + i * 16) * HID + h * VD + vv;
#pragma unroll
      for (int e = 0; e < 4; ++e) op[(size_t)e * HID] = gelu_f(acc[i][j][e]);
    }
  }
}

extern "C" void kernel_launch(void* const* d_in, const int* in_sizes, int n_in,
                              void* d_out, int out_size, void* d_ws, size_t ws_size,
                              hipStream_t stream) {
  const float* m_dist = (const float*)d_in[0];  // [8,2048,2048]
  const float* x      = (const float*)d_in[1];  // [16,2048,256]
  const float* r      = (const float*)d_in[2];  // [8]
  const float* weight = (const float*)d_in[3];  // [8,256,32]
  float* out = (float*)d_out;                   // [16,2048,256]

  // workspace: att bf16 (67.1 MB) + vT bf16 (16.8 MB)
  unsigned short* att = (unsigned short*)d_ws;
  unsigned short* vT  = (unsigned short*)((char*)d_ws + (size_t)NH * NQ * NKK * 2);

  fused_va_kernel<<<dim3(512 + NH * NQ), dim3(256), 0, stream>>>(x, weight, m_dist, r, vT, att);
  gemm_kernel<<<dim3(NH * 64), dim3(256), 0, stream>>>(att, vT, out);
}

// Round 6
// 103.731 us; speedup vs baseline: 1.3922x; 1.3922x over previous
//
#include <hip/hip_runtime.h>
#include <hip/hip_bf16.h>

#define NH   8
#define HID  256
#define VD   32
#define NQ   2048
#define NKK  2048
#define NB   16
#define NN   512   // NB*VD

typedef short bf16x8 __attribute__((ext_vector_type(8)));
typedef float f32x4 __attribute__((ext_vector_type(4)));

__device__ inline unsigned short f2bf(float f) {
  unsigned int u = __float_as_uint(f);
  u += 0x7FFFu + ((u >> 16) & 1u);   // RNE
  return (unsigned short)(u >> 16);
}

__device__ inline void gload_lds16(const void* g, void* l) {
  __builtin_amdgcn_global_load_lds(
      (const __attribute__((address_space(1))) void*)g,
      (__attribute__((address_space(3))) void*)l, 16, 0, 0);
}

__device__ inline float gelu_f(float x) {
  // jax.nn.gelu approximate: 0.5x(1+tanh(u)), tanh via exp (2u in [-20,20], no overflow)
  float u2 = 1.5957691216057308f * (x + 0.044715f * x * x * x);  // 2u
  float e = __expf(u2);
  return 0.5f * x * (1.0f + (e - 1.0f) / (e + 1.0f));
}

// LDS tile swizzle (T2): 16B slot s of row r holds logical slot s ^ ((r>>1)&3).

// ---------------- kernel 0: wT[h*32+v][j] = bf16(w[h][j][v])
__global__ __launch_bounds__(256) void wt_kernel(
    const float* __restrict__ w, unsigned short* __restrict__ wT) {
  const int n = blockIdx.x;        // 0..255 (h*32+v)
  const int j = threadIdx.x;       // 0..255
  wT[(size_t)n * HID + j] = f2bf(w[(size_t)(n >> 5) * HID * VD + (size_t)j * VD + (n & 31)]);
}

// ---------------- kernel 1: per-b MFMA GEMM: vT[(h,v)][k] = sum_j wT[(h,v)][j] * x[b][k][j]
__global__ __launch_bounds__(256) void value_kernel(
    const unsigned short* __restrict__ wT, const float* __restrict__ x,
    unsigned short* __restrict__ vT) {
  const int hvt = blockIdx.x & 1;      // 0..1  (hv tile)
  const int kt  = blockIdx.x >> 1;     // 0..15 (k tile)
  const int b   = blockIdx.y;          // 0..15
  const int m0 = hvt * 128;            // hv base
  const int n0 = kt * 128;             // k base
  const int t = threadIdx.x;
  const int lane = t & 63, wid = t >> 6;
  const int wr = wid >> 1, wc = wid & 1;

  __shared__ __align__(16) unsigned short As[128 * 32];
  __shared__ __align__(16) unsigned short Bs[128 * 32];

  // A staging via global_load_lds (wT is bf16, K-contig); source k pre-swizzled
  const int rowL = t >> 2;
  const int cb = (((t & 3) ^ ((t >> 3) & 3)) * 8);
  const unsigned short* gA0 = wT + (size_t)(m0 + rowL) * HID + cb;
  const unsigned short* gA1 = gA0 + (size_t)64 * HID;
  char* lA0 = (char*)As + t * 16;
  char* lA1 = (char*)As + 4096 + t * 16;

  // B staging via registers with f32->bf16 (x rows are k-cols of output)
  const int brow = t >> 1, bj = (t & 1) * 16;
  const float* gB = x + ((size_t)b * NKK + n0 + brow) * HID + bj;
  const int bc = (brow >> 1) & 3;
  const int bs0 = (2 * (t & 1)) ^ bc;          // physical 16B slot for first uint4
  unsigned short* lB0 = Bs + brow * 32 + bs0 * 8;
  unsigned short* lB1 = Bs + brow * 32 + (bs0 ^ 1) * 8;

  f32x4 acc[4][4];
#pragma unroll
  for (int i = 0; i < 4; ++i)
#pragma unroll
    for (int j = 0; j < 4; ++j) acc[i][j] = (f32x4){0.f, 0.f, 0.f, 0.f};

  const int fr = lane & 15;
  const int kb = (((lane >> 4) ^ ((fr >> 1) & 3)) * 16);   // swizzled read slot
  const char* baseA = (const char*)As + (wr * 64 + fr) * 64 + kb;
  const char* baseB = (const char*)Bs + (wc * 64 + fr) * 64 + kb;

  // prefetch B step 0
  f32x4 p0 = *(const f32x4*)(gB + 0);
  f32x4 p1 = *(const f32x4*)(gB + 4);
  f32x4 p2 = *(const f32x4*)(gB + 8);
  f32x4 p3 = *(const f32x4*)(gB + 12);

  for (int kk = 0; kk < HID / 32; ++kk) {
    gload_lds16(gA0, lA0);
    gload_lds16(gA1, lA1);
    gA0 += 32; gA1 += 32;

    f32x4 c0 = p0, c1 = p1, c2 = p2, c3 = p3;
    if (kk < HID / 32 - 1) {
      const float* nb = gB + (kk + 1) * 32;
      p0 = *(const f32x4*)(nb + 0);
      p1 = *(const f32x4*)(nb + 4);
      p2 = *(const f32x4*)(nb + 8);
      p3 = *(const f32x4*)(nb + 12);
    }
    uint4 pk0, pk1;
    pk0.x = (unsigned)f2bf(c0[0]) | ((unsigned)f2bf(c0[1]) << 16);
    pk0.y = (unsigned)f2bf(c0[2]) | ((unsigned)f2bf(c0[3]) << 16);
    pk0.z = (unsigned)f2bf(c1[0]) | ((unsigned)f2bf(c1[1]) << 16);
    pk0.w = (unsigned)f2bf(c1[2]) | ((unsigned)f2bf(c1[3]) << 16);
    pk1.x = (unsigned)f2bf(c2[0]) | ((unsigned)f2bf(c2[1]) << 16);
    pk1.y = (unsigned)f2bf(c2[2]) | ((unsigned)f2bf(c2[3]) << 16);
    pk1.z = (unsigned)f2bf(c3[0]) | ((unsigned)f2bf(c3[1]) << 16);
    pk1.w = (unsigned)f2bf(c3[2]) | ((unsigned)f2bf(c3[3]) << 16);
    *(uint4*)lB0 = pk0;
    *(uint4*)lB1 = pk1;

    __syncthreads();   // drains vmcnt (gload_lds) + lgkm (ds_write)

    bf16x8 a[4], bfr[4];
#pragma unroll
    for (int i = 0; i < 4; ++i) a[i] = *(const bf16x8*)(baseA + i * 16 * 64);
#pragma unroll
    for (int j = 0; j < 4; ++j) bfr[j] = *(const bf16x8*)(baseB + j * 16 * 64);
#pragma unroll
    for (int i = 0; i < 4; ++i)
#pragma unroll
      for (int j = 0; j < 4; ++j)
        acc[i][j] = __builtin_amdgcn_mfma_f32_16x16x32_bf16(a[i], bfr[j], acc[i][j], 0, 0, 0);
    __syncthreads();
  }

  // epilogue: C[m=hv][n=k]; D row=(lane>>4)*4+e (A-row), col=lane&15 (B-row)
  const int hvb = m0 + wr * 64 + (lane >> 4) * 4;
  const int kc0 = n0 + wc * 64 + (lane & 15);
#pragma unroll
  for (int i = 0; i < 4; ++i) {
#pragma unroll
    for (int j = 0; j < 4; ++j) {
      int kc = kc0 + j * 16;
#pragma unroll
      for (int e = 0; e < 4; ++e) {
        int hv = hvb + i * 16 + e;
        int h = hv >> 5, v = hv & 31;
        vT[((size_t)h * NN + b * VD + v) * NKK + kc] = f2bf(acc[i][j][e]);
      }
    }
  }
}

// ---------------- kernel 2: ONE WAVE PER (h,q) ROW — barrier-free median + softmax
__global__ __launch_bounds__(256) void att_kernel(
    const float* __restrict__ m_dist, const float* __restrict__ r,
    unsigned short* __restrict__ att) {
  const int w = threadIdx.x >> 6;      // wave 0..3
  const int lane = threadIdx.x & 63;
  const int row = (blockIdx.x << 2) | w;   // h*NQ + q
  const int h = row >> 11;

  __shared__ unsigned int histS[4][256];
  __shared__ float collS[4][160];
  __shared__ unsigned int cntS[4];
  __shared__ float vabS[4][2];

  unsigned int* hist = histS[w];
  float* coll = collS[w];

  const float C = (float)(0.25 * 3.141592653589793 * (1.0 - 1e-7));
  float sc = tanf(C * (1.0f + sinf(r[h])));

  *(uint4*)&hist[lane * 4] = (uint4){0u, 0u, 0u, 0u};
  if (lane == 0) cntS[w] = 0u;

  const float* md = m_dist + (size_t)row * NKK;
  f32x4 m4[8];
#pragma unroll
  for (int k = 0; k < 8; ++k) m4[k] = *(const f32x4*)(md + 4 * lane + 256 * k);

  float mn = 1e30f;
#pragma unroll
  for (int k = 0; k < 8; ++k)
#pragma unroll
    for (int e = 0; e < 4; ++e) {
      float v = m4[k][e];
      mn = fminf(mn, v);
      int bin = min(max((int)(v * 256.0f), 0), 255);
      atomicAdd(&hist[bin], 1u);
    }
#pragma unroll
  for (int off = 32; off; off >>= 1) mn = fminf(mn, __shfl_xor(mn, off));

  asm volatile("s_waitcnt lgkmcnt(0)" ::: "memory");   // wave-local hist complete
  uint4 hc = *(const uint4*)&hist[lane * 4];           // lane owns bins 4l..4l+3
  unsigned c0 = hc.x, c1 = hc.x + hc.y, c2 = c1 + hc.z, c3 = c2 + hc.w;
  unsigned g = c3;
  unsigned incl = g;
#pragma unroll
  for (int off = 1; off < 64; off <<= 1) {
    unsigned y = __shfl_up(incl, off);
    if (lane >= off) incl += y;
  }
  unsigned excl = incl - g;

  // locate bin of rank 1023 (bA, below) and rank 1024 (bB)
  unsigned long long ba1 = __ballot(incl >= 1024u);
  int glA = __ffsll((unsigned long long)ba1) - 1;
  unsigned eA = __shfl(excl, glA);
  unsigned a0 = __shfl(excl + c0, glA), a1 = __shfl(excl + c1, glA), a2 = __shfl(excl + c2, glA);
  int bA; unsigned below;
  if (a0 >= 1024u)      { bA = glA * 4 + 0; below = eA; }
  else if (a1 >= 1024u) { bA = glA * 4 + 1; below = a0; }
  else if (a2 >= 1024u) { bA = glA * 4 + 2; below = a1; }
  else                  { bA = glA * 4 + 3; below = a2; }
  unsigned long long ba2 = __ballot(incl >= 1025u);
  int glB = __ffsll((unsigned long long)ba2) - 1;
  unsigned e0 = __shfl(excl + c0, glB), e1 = __shfl(excl + c1, glB), e2 = __shfl(excl + c2, glB);
  int bB = (e0 >= 1025u) ? glB * 4 : (e1 >= 1025u) ? glB * 4 + 1
                                   : (e2 >= 1025u) ? glB * 4 + 2 : glB * 4 + 3;

  // collect candidates in [bA,bB]
#pragma unroll
  for (int k = 0; k < 8; ++k)
#pragma unroll
    for (int e = 0; e < 4; ++e) {
      float v = m4[k][e];
      int bin = min(max((int)(v * 256.0f), 0), 255);
      if (bin >= bA && bin <= bB) {
        unsigned idx = atomicAdd(&cntS[w], 1u);
        if (idx < 160u) coll[idx] = v;
      }
    }
  asm volatile("s_waitcnt lgkmcnt(0)" ::: "memory");
  const int n = (int)min(cntS[w], 160u);
  const int ra = 1023 - (int)below, rb = 1024 - (int)below;
#pragma unroll
  for (int e2 = 0; e2 < 3; ++e2) {
    int idx = lane + (e2 << 6);
    if (idx < n) {
      float v = coll[idx];
      int rank = 0;
      for (int j2 = 0; j2 < n; ++j2) {
        float u = coll[j2];
        rank += (u < v || (u == v && j2 < idx)) ? 1 : 0;  // stable rank
      }
      if (rank == ra) vabS[w][0] = v;
      if (rank == rb) vabS[w][1] = v;
    }
  }
  asm volatile("s_waitcnt lgkmcnt(0)" ::: "memory");
  float thr = 0.5f * (vabS[w][0] * sc) + 0.5f * (vabS[w][1] * sc);
  float minscaled = mn * sc;

  float wsum = 0.f;
#pragma unroll
  for (int k = 0; k < 8; ++k)
#pragma unroll
    for (int e = 0; e < 4; ++e) {
      float s = m4[k][e] * sc;
      float ev = (s <= thr) ? __expf(minscaled - s) : 0.f;
      m4[k][e] = ev;
      wsum += ev;
    }
#pragma unroll
  for (int off = 32; off; off >>= 1) wsum += __shfl_xor(wsum, off);
  float inv = 1.0f / wsum;

  unsigned short* ao = att + (size_t)row * NKK;
#pragma unroll
  for (int k = 0; k < 8; ++k) {
    uint2 pk;
    pk.x = (unsigned)f2bf(m4[k][0] * inv) | ((unsigned)f2bf(m4[k][1] * inv) << 16);
    pk.y = (unsigned)f2bf(m4[k][2] * inv) | ((unsigned)f2bf(m4[k][3] * inv) << 16);
    *(uint2*)(ao + 4 * lane + 256 * k) = pk;
  }
}

// ---------------- kernel 3: per head GEMM: C[q, n] = att[h] @ vT[h]^T, + gelu, scattered out
// depth-3 pipelined: 4 LDS buffer pairs, counted vmcnt(8), one barrier per K-step
__global__ __launch_bounds__(256) void gemm_kernel(
    const unsigned short* __restrict__ att, const unsigned short* __restrict__ vT,
    float* __restrict__ out) {
  const int bid = blockIdx.x;
  const int h = bid & 7;           // XCD = bid%8 -> one head per XCD (B panel L2-resident)
  const int tile = bid >> 3;       // 0..63
  const int qt = tile >> 2, nt = tile & 3;
  const int q0 = qt * 128, n0 = nt * 128;
  const int t = threadIdx.x;
  const int lane = t & 63, wid = t >> 6;
  const int wr = wid >> 1, wc = wid & 1;

  __shared__ __align__(16) unsigned short As[4][128 * 32];
  __shared__ __align__(16) unsigned short Bs[4][128 * 32];

  const int rowL = t >> 2;          // 0..63
  const int cb = (((t & 3) ^ ((t >> 3) & 3)) * 8);   // pre-swizzled source k offset

  const unsigned short* gA = att + ((size_t)h * NQ + q0 + rowL) * NKK + cb;
  const unsigned short* gB = vT + ((size_t)h * NN + n0 + rowL) * NKK + cb;
  const int ldsOff = t * 16;

#define STAGE(BI, KT) do {                                                  \
    const unsigned short* a_ = gA + (KT) * 32;                              \
    const unsigned short* b_ = gB + (KT) * 32;                              \
    char* lA_ = (char*)As[(BI)] + ldsOff;                                   \
    char* lB_ = (char*)Bs[(BI)] + ldsOff;                                   \
    gload_lds16(a_, lA_);                                                   \
    gload_lds16(a_ + (size_t)64 * NKK, lA_ + 4096);                         \
    gload_lds16(b_, lB_);                                                   \
    gload_lds16(b_ + (size_t)64 * NKK, lB_ + 4096);                         \
  } while (0)

  f32x4 acc[4][4];
#pragma unroll
  for (int i = 0; i < 4; ++i)
#pragma unroll
    for (int j = 0; j < 4; ++j) acc[i][j] = (f32x4){0.f, 0.f, 0.f, 0.f};

  const int fr = lane & 15;
  const int kb = (((lane >> 4) ^ ((fr >> 1) & 3)) * 16);   // swizzled read slot
  const int fragOff = (wr * 64 + fr) * 64 + kb;   // A-side byte offset
  const int fragOffB = (wc * 64 + fr) * 64 + kb;  // B-side byte offset

  // prologue: 3 tiles in flight
  STAGE(0, 0);
  STAGE(1, 1);
  STAGE(2, 2);
  asm volatile("s_waitcnt vmcnt(8)\n\ts_barrier" ::: "memory");  // tile 0 ready

  for (int kt = 0; kt < 64; kt += 4) {
#pragma unroll
    for (int u = 0; u < 4; ++u) {
      // frag reads from buffer u (tile kt+u)
      const char* bA = (const char*)As[u] + fragOff;
      const char* bB = (const char*)Bs[u] + fragOffB;
      bf16x8 a[4], b[4];
#pragma unroll
      for (int i = 0; i < 4; ++i) a[i] = *(const bf16x8*)(bA + i * 1024);
#pragma unroll
      for (int j = 0; j < 4; ++j) b[j] = *(const bf16x8*)(bB + j * 1024);
      // stage tile kt+u+3 into buffer (u+3)&3 (consumed last sub-iter); wrap at tail
      STAGE((u + 3) & 3, (kt + u + 3) & 63);
      __builtin_amdgcn_s_setprio(1);
#pragma unroll
      for (int i = 0; i < 4; ++i)
#pragma unroll
        for (int j = 0; j < 4; ++j)
          acc[i][j] = __builtin_amdgcn_mfma_f32_16x16x32_bf16(a[i], b[j], acc[i][j], 0, 0, 0);
      __builtin_amdgcn_s_setprio(0);
      // keep 8 loads (2 tiles) in flight; oldest tile (next to read) retired
      asm volatile("s_waitcnt vmcnt(8)\n\ts_barrier" ::: "memory");
    }
  }
  // drain junk tail stages before LDS deallocates / epilogue
  asm volatile("s_waitcnt vmcnt(0)" ::: "memory");
#undef STAGE

  // epilogue: D row=(lane>>4)*4+reg, col=lane&15 ; n -> (b, v) ; out[b, q, h*32+v]
  const int orow = q0 + wr * 64 + (lane >> 4) * 4;
  const int ocol0 = n0 + wc * 64 + (lane & 15);
#pragma unroll
  for (int i = 0; i < 4; ++i) {
#pragma unroll
    for (int j = 0; j < 4; ++j) {
      int ncol = ocol0 + j * 16;
      int bb = ncol >> 5, vv = ncol & 31;
      float* op = out + ((size_t)bb * NQ + orow + i * 16) * HID + h * VD + vv;
#pragma unroll
      for (int e = 0; e < 4; ++e) op[(size_t)e * HID] = gelu_f(acc[i][j][e]);
    }
  }
}

extern "C" void kernel_launch(void* const* d_in, const int* in_sizes, int n_in,
                              void* d_out, int out_size, void* d_ws, size_t ws_size,
                              hipStream_t stream) {
  const float* m_dist = (const float*)d_in[0];  // [8,2048,2048]
  const float* x      = (const float*)d_in[1];  // [16,2048,256]
  const float* r      = (const float*)d_in[2];  // [8]
  const float* weight = (const float*)d_in[3];  // [8,256,32]
  float* out = (float*)d_out;                   // [16,2048,256]

  // workspace: att bf16 (67.1 MB) + vT bf16 (16.8 MB) + wT bf16 (128 KB)
  unsigned short* att = (unsigned short*)d_ws;
  unsigned short* vT  = (unsigned short*)((char*)d_ws + (size_t)NH * NQ * NKK * 2);
  unsigned short* wT  = (unsigned short*)((char*)d_ws + (size_t)NH * NQ * NKK * 2 +
                                          (size_t)NH * NN * NKK * 2);

  wt_kernel<<<dim3(256), dim3(256), 0, stream>>>(weight, wT);
  value_kernel<<<dim3(32, NB), dim3(256), 0, stream>>>(wT, x, vT);
  att_kernel<<<dim3(NH * NQ / 4), dim3(256), 0, stream>>>(m_dist, r, att);
  gemm_kernel<<<dim3(NH * 64), dim3(256), 0, stream>>>(att, vT, out);
}